// Round 14
// baseline (5774.607 us; speedup 1.0000x reference)
//
#include <hip/hip_runtime.h>
#include <math.h>

// Deep ESN, fp32, persistent wavefront-pipelined kernel, round 21.
// R20 (JW=8, 2 blocks/CU) proved: (a) 4 waves/SIMD fully overlaps VALU under
// memory (tick == mem time), (b) the fabric serves ~11 TB/s coherent reads,
// (c) a 32-float-acc body fits VGPR=64 WITHOUT spilling. But R20 doubled its
// own traffic (128MB/tick). R21 combines 4 waves/SIMD WITH 64MB/tick:
// 1024-thread blocks (256 blocks = 64 readers/layer), JW=16, 4-way k-split,
// and 8B state loads so acc stays 32 floats (VGPR-64-safe; R9's spill was
// the 64-float acc). Each lane reads its own 64B weight row -> the 8-DPP/iter
// weight repack disappears. Reduce = 4-stage ladder over 16 kq-lanes;
// 4-quarter combine via 6KB Pbuf (R9's verified NKH=4 pattern).

#define TT    512
#define RDIM  1024
#define EDIM  256
#define NL    4
#define BB    32
#define NBLK  256          // 4 layers x 64 colgroups
#define JW    16           // output columns per block
#define HDIM  (RDIM * NL)  // 4096
#define NPAN  4            // 4 panels of 8 batch rows
#define NKH   4            // k-split ways
#define CSTRIDE 32         // dwords between counter words (128B lines)

#define S_ELEMS   (2 * NL * NPAN * RDIM * 8)   // 2 parities, 1MB
#define FIN_ELEMS (BB * HDIM)

typedef float vf2 __attribute__((ext_vector_type(2)));

typedef unsigned long long ull;

// 8B coherent load (bypass L1+L2 -> MALL), issue only, no wait.
__device__ __forceinline__ void gload2_sc(vf2& d, const void* p) {
    asm volatile("global_load_dwordx2 %0, %1, off sc0 sc1" : "=v"(d) : "v"(p));
}
// 8B plain cached load (xe: read-only input, L2-cacheable), issue only.
__device__ __forceinline__ void gload2_pl(vf2& d, const void* p) {
    asm volatile("global_load_dwordx2 %0, %1, off" : "=v"(d) : "v"(p));
}
// Counted wait, data-tied to the buffer being consumed.
__device__ __forceinline__ void vwait2(int wn, vf2& r) {
    if (wn >= 7)      asm volatile("s_waitcnt vmcnt(7)" : "+v"(r));
    else if (wn == 6) asm volatile("s_waitcnt vmcnt(6)" : "+v"(r));
    else if (wn == 5) asm volatile("s_waitcnt vmcnt(5)" : "+v"(r));
    else if (wn == 4) asm volatile("s_waitcnt vmcnt(4)" : "+v"(r));
    else if (wn == 3) asm volatile("s_waitcnt vmcnt(3)" : "+v"(r));
    else if (wn == 2) asm volatile("s_waitcnt vmcnt(2)" : "+v"(r));
    else if (wn == 1) asm volatile("s_waitcnt vmcnt(1)" : "+v"(r));
    else              asm volatile("s_waitcnt vmcnt(0)" : "+v"(r));
}

// ---------------------------------------------------------------- gather ----
// xe[t][panel][k][8b] : panel layout matching reservoir reads
__global__ void gather_kernel(const int* __restrict__ x,
                              const float* __restrict__ embed,
                              float* __restrict__ xe)
{
    __shared__ int   ids[BB];
    __shared__ float sh[BB * (EDIM + 1)];
    const int t = blockIdx.x, tid = threadIdx.x;
    if (tid < BB) ids[tid] = x[tid * TT + t];
    __syncthreads();
    for (int r = 0; r < BB; ++r)
        sh[r * (EDIM + 1) + tid] = embed[ids[r] * EDIM + tid];
    __syncthreads();
    for (int i = tid; i < NPAN * EDIM * 8; i += 256) {
        int p = i >> 11, k = (i >> 3) & (EDIM - 1), bo = i & 7;
        xe[(size_t)t * (NPAN * EDIM * 8) + i] = sh[(p * 8 + bo) * (EDIM + 1) + k];
    }
}

// ------------------------------------------------- per-tick compute body ----
// Depth-8 pipelined 8B MALL loads. Wave covers 16 rows/iter (kq=lam>>2);
// lane holds 2 batch values (bq=lam&3) and reads its own 16-col weight row.
// acc[i][jp] = batch (bq*2+i) x cols (2jp, 2jp+1).
template<int NI, bool SCIN>
__device__ __forceinline__ void tick_body(
    const float* __restrict__ Sown, const float* __restrict__ Sin,
    const float* __restrict__ Wlds,
    const int k4, const int kq, const int bq,
    vf2 acc[2][8])
{
    constexpr int NOWN = 16;            // own iters (256 rows / 16 per iter)
    constexpr int NT   = NOWN + NI;

    const ull* ownp = (const ull*)Sown;
    const ull* inp  = (const ull*)Sin;
    const int obase = k4 * 1024 + kq * 4 + bq;       // ull units
    const int ibase = k4 * (NI * 64) + kq * 4 + bq;  // ull units

    vf2 b[8];

    // prologue: fill the 8-deep queue (first 8 loads are all own-segment)
    #pragma unroll
    for (int i = 0; i < 8; ++i)
        gload2_sc(b[i], (const void*)(ownp + obase + i * 64));

    #pragma unroll
    for (int i = 0; i < NT; ++i) {
        vf2& br = b[i & 7];
        const int wn = (NT - 1 - i) < 7 ? (NT - 1 - i) : 7;
        vwait2(wn, br);
        const vf2 v = br;
        if (i + 8 < NT) {
            const int n = i + 8;
            if (n < NOWN) {
                gload2_sc(br, (const void*)(ownp + obase + n * 64));
            } else {
                const void* p = (const void*)(inp + ibase + (n - NOWN) * 64);
                if (SCIN) gload2_sc(br, p);
                else      gload2_pl(br, p);
            }
        }
        // weight row for this lane's k-row
        const int wrow = (i < NOWN) ? (k4 * 256 + i * 16 + kq)
                                    : (RDIM + k4 * (NI * 16) + (i - NOWN) * 16 + kq);
        const float* wr = &Wlds[wrow * JW];
        const float vv[2] = {v.x, v.y};
        {   // cols 0..7
            float4 a0 = *(const float4*)wr;
            float4 a1 = *(const float4*)(wr + 4);
            vf2 wv[4];
            wv[0] = (vf2){a0.x, a0.y}; wv[1] = (vf2){a0.z, a0.w};
            wv[2] = (vf2){a1.x, a1.y}; wv[3] = (vf2){a1.z, a1.w};
            #pragma unroll
            for (int q = 0; q < 2; ++q) {
                vf2 s = {vv[q], vv[q]};
                #pragma unroll
                for (int jp = 0; jp < 4; ++jp) acc[q][jp] += s * wv[jp];
            }
        }
        {   // cols 8..15 (reuse weight registers)
            float4 c0 = *(const float4*)(wr + 8);
            float4 c1 = *(const float4*)(wr + 12);
            vf2 wv[4];
            wv[0] = (vf2){c0.x, c0.y}; wv[1] = (vf2){c0.z, c0.w};
            wv[2] = (vf2){c1.x, c1.y}; wv[3] = (vf2){c1.z, c1.w};
            #pragma unroll
            for (int q = 0; q < 2; ++q) {
                vf2 s = {vv[q], vv[q]};
                #pragma unroll
                for (int jp = 0; jp < 4; ++jp) acc[q][4 + jp] += s * wv[jp];
            }
        }
    }
}

// ---- reduce over the 16 kq-lanes: 32 accs -> 2 finals per lane ----
// idx = i*16 + c (i=batch slot, c=col). Stage s consumes idx bit s with
// lane bit (2+s) (xor dist 4<<s). Final: lane kq holds (batch bq*2+m, col kq).
__device__ __forceinline__ void reduce32q(const vf2 acc[2][8], const int kq,
                                          float rfin[2])
{
    float r32v[32];
    #pragma unroll
    for (int i = 0; i < 2; ++i)
        #pragma unroll
        for (int jp = 0; jp < 8; ++jp) {
            r32v[(i << 4) | (jp << 1)]     = acc[i][jp].x;
            r32v[(i << 4) | (jp << 1) | 1] = acc[i][jp].y;
        }
    float r16v[16], r8v[8], r4v[4];
    {   const bool myb = kq & 1;                 // stage 0: xor 4
        #pragma unroll
        for (int m = 0; m < 16; ++m) {
            float a = r32v[2 * m], b = r32v[2 * m + 1];
            float send = myb ? a : b, keep = myb ? b : a;
            r16v[m] = keep + __shfl_xor(send, 4, 64);
        }
    }
    {   const bool myb = (kq >> 1) & 1;          // stage 1: xor 8
        #pragma unroll
        for (int m = 0; m < 8; ++m) {
            float a = r16v[2 * m], b = r16v[2 * m + 1];
            float send = myb ? a : b, keep = myb ? b : a;
            r8v[m] = keep + __shfl_xor(send, 8, 64);
        }
    }
    {   const bool myb = (kq >> 2) & 1;          // stage 2: xor 16
        #pragma unroll
        for (int m = 0; m < 4; ++m) {
            float a = r8v[2 * m], b = r8v[2 * m + 1];
            float send = myb ? a : b, keep = myb ? b : a;
            r4v[m] = keep + __shfl_xor(send, 16, 64);
        }
    }
    {   const bool myb = (kq >> 3) & 1;          // stage 3: xor 32
        #pragma unroll
        for (int m = 0; m < 2; ++m) {
            float a = r4v[2 * m], b = r4v[2 * m + 1];
            float send = myb ? a : b, keep = myb ? b : a;
            rfin[m] = keep + __shfl_xor(send, 32, 64);
        }
    }
}

// ------------------------------------------------------------- reservoir ----
__global__ __launch_bounds__(1024) void reservoir_kernel(
    const float* __restrict__ Win0, const float* __restrict__ WinR,
    const float* __restrict__ Rst,  const float* __restrict__ xe,
    float* __restrict__ S, float* __restrict__ Fin,
    unsigned* __restrict__ cnt, unsigned* __restrict__ rel)
{
    __shared__ float Wlds[2048 * JW];                  // 128 KB, row k = 16 floats
    __shared__ float Pbuf[(NKH - 1) * NPAN * JW * 8];  // 6 KB, quarter partials
    const int tid   = threadIdx.x;
    const int blk   = blockIdx.x;
    const int layer = blk >> 6;
    const int g     = blk & 63;
    const int j0    = g * JW;
    const int Kin   = (layer == 0) ? EDIM : RDIM;

    // rows [0,1024) = R_stack col-slice, rows [1024,1024+Kin) = Win col-slice
    for (int idx = tid; idx < (RDIM + Kin) * JW; idx += 1024) {
        int k = idx >> 4, j = idx & 15;
        float wv;
        if (k < RDIM) wv = Rst[((size_t)layer * RDIM + k) * RDIM + j0 + j];
        else {
            int k2 = k - RDIM;
            wv = (layer == 0) ? Win0[(size_t)k2 * RDIM + j0 + j]
                              : WinR[((size_t)(layer - 1) * RDIM + k2) * RDIM + j0 + j];
        }
        Wlds[idx] = wv;
    }
    __syncthreads();

    const int w16 = tid >> 6;   // 16 waves
    const int w   = w16 & 3;    // panel (8 batch rows)
    const int k4  = w16 >> 2;   // k-quarter: wave reads a disjoint k-slice
    const int lam = tid & 63;
    const int kq  = lam >> 2;   // 16 k-rows per iteration
    const int bq  = lam & 3;    // batch pair (2 of the panel's 8 rows)

    for (int tick = 0; tick < TT + NL - 1; ++tick) {
        const int t = tick - layer;
        if (t >= 0 && t < TT) {
            const int cur = tick & 1, prv = (tick - 1) & 1;
            const float* Sown = S + (((size_t)(prv * NL + layer)) * NPAN + w) * RDIM * 8;
            const float* Sin  = (layer == 0)
                ? (xe + ((size_t)t * NPAN + w) * (EDIM * 8))
                : (S + (((size_t)(prv * NL + layer - 1)) * NPAN + w) * RDIM * 8);

            vf2 acc[2][8];
            #pragma unroll
            for (int i = 0; i < 2; ++i)
                #pragma unroll
                for (int jp = 0; jp < 8; ++jp) acc[i][jp] = (vf2)(0.f);

            if (layer == 0) tick_body<4,  false>(Sown, Sin, Wlds, k4, kq, bq, acc);
            else            tick_body<16, true >(Sown, Sin, Wlds, k4, kq, bq, acc);

            float rfin[2];
            reduce32q(acc, kq, rfin);

            // ---- cross-wave quarter combine via LDS, then epilogue ----
            if (k4) {                               // quarters 1..3: publish
                #pragma unroll
                for (int m = 0; m < 2; ++m)
                    Pbuf[((((k4 - 1) * NPAN + w) * JW + kq) << 3) + bq * 2 + m] = rfin[m];
            }
            __syncthreads();                        // block-uniform (t uniform)
            if (!k4) {                              // quarter 0: combine + store
                float* sbase = S + (((size_t)(cur * NL + layer)) * NPAN + w) * RDIM * 8
                                 + (size_t)(j0 + kq) * 8;
                #pragma unroll
                for (int m = 0; m < 2; ++m) {
                    const int bi = bq * 2 + m;      // slot within panel's 8
                    float v = rfin[m];
                    #pragma unroll
                    for (int q = 1; q < NKH; ++q)
                        v += Pbuf[((((q - 1) * NPAN + w) * JW + kq) << 3) + bi];
                    const float o = tanhf(v);
                    // sc1 store: direct to MALL, drained by pre-barrier vmcnt(0)
                    __hip_atomic_store(sbase + bi, o, __ATOMIC_RELAXED, __HIP_MEMORY_SCOPE_AGENT);
                    if (t == TT - 1)
                        Fin[(size_t)(w * 8 + bi) * HDIM + layer * RDIM + j0 + kq] = o;
                }
            }
        }
        // ---- grid barrier v3: spread arrive, single summer, replicated
        //      release lines, 1-lane backoff polls (no poll storm) ----
        __syncthreads();                          // drains all waves' stores
        if (tid == 0)
            __hip_atomic_fetch_add(&cnt[(blk & 15) * CSTRIDE], 1u,
                                   __ATOMIC_RELAXED, __HIP_MEMORY_SCOPE_AGENT);
        const unsigned wrel = (unsigned)(tick + 1);
        if (blk == 0) {
            if (tid < 64) {                       // summer wave
                const unsigned wsum = wrel * (unsigned)NBLK;
                int guard = 0;
                for (;;) {
                    unsigned v = 0;
                    if (lam < 16)
                        v = __hip_atomic_load(&cnt[lam * CSTRIDE],
                                              __ATOMIC_RELAXED, __HIP_MEMORY_SCOPE_AGENT);
                    #pragma unroll
                    for (int m = 1; m <= 32; m <<= 1) v += __shfl_xor(v, m, 64);
                    if (v >= wsum) break;         // v is total on ALL lanes
                    __builtin_amdgcn_s_sleep(2);
                    if (++guard > (1 << 16)) break;   // safety valve
                }
                if (lam < 16)                     // publish release, 16 copies
                    __hip_atomic_store(&rel[lam * CSTRIDE], wrel,
                                       __ATOMIC_RELAXED, __HIP_MEMORY_SCOPE_AGENT);
            }
        } else {
            if (tid == 0) {                       // one poller lane per block
                int guard = 0;
                while (__hip_atomic_load(&rel[(blk & 15) * CSTRIDE],
                                         __ATOMIC_RELAXED, __HIP_MEMORY_SCOPE_AGENT) < wrel) {
                    __builtin_amdgcn_s_sleep(4);
                    if (++guard > (1 << 16)) break;   // safety valve
                }
            }
        }
        __syncthreads();
    }
}

// ------------------------------------------------------------- layernorm ----
__global__ void ln_kernel(const float* __restrict__ Fin,
                          const float* __restrict__ gamma,
                          const float* __restrict__ beta,
                          float* __restrict__ out)
{
    const int r = blockIdx.x, tid = threadIdx.x;
    const float* row = Fin + (size_t)r * HDIM;
    float s = 0.f, s2 = 0.f;
    for (int i = tid; i < HDIM; i += 256) { float v = row[i]; s += v; s2 += v * v; }
    for (int off = 32; off; off >>= 1) {
        s  += __shfl_down(s,  off, 64);
        s2 += __shfl_down(s2, off, 64);
    }
    __shared__ float rs[4], rs2[4];
    __shared__ float mu_s, rstd_s;
    if ((tid & 63) == 0) { rs[tid >> 6] = s; rs2[tid >> 6] = s2; }
    __syncthreads();
    if (tid == 0) {
        float S1 = rs[0] + rs[1] + rs[2] + rs[3];
        float S2 = rs2[0] + rs2[1] + rs2[2] + rs2[3];
        float mu = S1 / (float)HDIM;
        float var = S2 / (float)HDIM - mu * mu;
        mu_s = mu; rstd_s = rsqrtf(var + 1e-5f);
    }
    __syncthreads();
    float mu = mu_s, rstd = rstd_s;
    for (int i = tid; i < HDIM; i += 256)
        out[(size_t)r * HDIM + i] = (row[i] - mu) * rstd * gamma[i] + beta[i];
}

// ----------------------------------------------------------------- launch ---
extern "C" void kernel_launch(void* const* d_in, const int* in_sizes, int n_in,
                              void* d_out, int out_size, void* d_ws, size_t ws_size,
                              hipStream_t stream)
{
    const int*   x     = (const int*)d_in[0];
    const float* embed = (const float*)d_in[1];
    const float* Win0  = (const float*)d_in[2];
    const float* WinR  = (const float*)d_in[3];
    const float* Rst   = (const float*)d_in[4];
    const float* gamma = (const float*)d_in[5];
    const float* beta  = (const float*)d_in[6];
    float* out = (float*)d_out;

    char* ws = (char*)d_ws;
    unsigned* cnt = (unsigned*)ws;                    // 16 lines (arrive)
    unsigned* rel = cnt + 16 * CSTRIDE;               // 16 lines (release)
    float* S   = (float*)(ws + 8192);                                // 1MB
    float* Fin = S + S_ELEMS;                                        // 0.5MB
    float* xe  = Fin + FIN_ELEMS;                                    // 16.8MB

    hipMemsetAsync(ws, 0, 8192 + (size_t)S_ELEMS * 4, stream);       // flags+states
    gather_kernel   <<<TT,   256, 0, stream>>>(x, embed, xe);
    reservoir_kernel<<<NBLK, 1024, 0, stream>>>(Win0, WinR, Rst, xe, S, Fin, cnt, rel);
    ln_kernel       <<<BB,   256, 0, stream>>>(Fin, gamma, beta, out);
}